// Round 12
// baseline (256.719 us; speedup 1.0000x reference)
//
#include <hip/hip_runtime.h>

// Problem constants (from reference): M=8 samples, N=4096, K=16 filters.
#define NN 4096
#define MM 8
#define KK 16

// Native clang vector type (HIP float4 struct is rejected by
// __builtin_nontemporal_load; ext vectors get componentwise ops).
typedef float v4f __attribute__((ext_vector_type(4)));

// ws layout (floats; all write-before-read every call except ctr, memset'd):
//   col     @ 0        : 4096 floats (16 KB)
//   partial @ 4096     : 64 x 4096 floats (1 MB), partial[rg][m]
//   Wt      @ 266240   : 4096 x 16 floats (256 KB), Wt[i][k]
//   ctr     @ 331776   : 16 ints (64 B) — per-stripe completion counters
#define WS_COL     0
#define WS_PARTIAL 4096
#define WS_WT      (4096 + 64 * 4096)
#define WS_CTR     (WS_WT + NN * KK)

// Fused stage 1: grid (16, 65).
//  y<64 : partial[y][stripe x] = sum of 64 rows of L; then per-stripe
//         last-finisher (ctr[x] idx==63) reduces the stripe into col —
//         the col-reduce rides stage1's tail instead of a separate
//         dispatch (saves stage2 + one inter-kernel gap).
//  y==64: Wt[i][k] = W[k][i] transpose (independent of L).
// Memory-model: writer blocks release partials via __threadfence() before
// atomicAdd (device-scope); the idx==63 block acquires via __threadfence()
// after the RMW. Output arithmetic is a fixed-order reduction -> result is
// deterministic regardless of block finish order.
__global__ void __launch_bounds__(256) colsum_fused(const float* __restrict__ L,
                                                    const float* __restrict__ W,
                                                    float* __restrict__ ws) {
    const int t = threadIdx.x;
    if (blockIdx.y == 64) {
        float* __restrict__ Wt = ws + WS_WT;
        for (int o = blockIdx.x * 256 + t; o < NN * KK; o += 16 * 256) {
            const int i = o >> 4;                    // simplex index
            const int k = o & 15;                    // filter index
            Wt[o] = W[k * NN + i];
        }
        return;
    }
    const int bx = blockIdx.x;                        // column stripe 0..15
    const int m4 = bx * 64 + (t & 63);                // float4 column slot
    const int r0 = blockIdx.y * 64 + (t >> 6) * 16;   // this thread's 16 rows
    const v4f* __restrict__ L4 = reinterpret_cast<const v4f*>(L);
    v4f acc = {0.f, 0.f, 0.f, 0.f};
#pragma unroll
    for (int j = 0; j < 16; ++j) {
        acc += __builtin_nontemporal_load(&L4[(size_t)(r0 + j) * (NN / 4) + m4]);
    }
    __shared__ v4f red[256];
    __shared__ int s_idx;
    red[t] = acc;
    __syncthreads();
    v4f* __restrict__ p4 = reinterpret_cast<v4f*>(ws + WS_PARTIAL);
    if (t < 64) {   // wave 0 only: holds ALL partial stores of this block
        const v4f s = red[t] + red[t + 64] + red[t + 128] + red[t + 192];
        p4[blockIdx.y * (NN / 4) + bx * 64 + t] = s;
    }
    __threadfence();                                  // release partial stores
    if (t == 0) {
        s_idx = atomicAdd((int*)(ws + WS_CTR) + bx, 1);
    }
    __syncthreads();
    if (s_idx != 63) return;                          // not the last finisher

    // Last finisher for stripe bx: all 64 row-group partials are visible.
    __threadfence();                                  // acquire
    const int q    = t >> 6;                          // row-group quarter
    const int slot = bx * 64 + (t & 63);
    v4f a2 = {0.f, 0.f, 0.f, 0.f};
#pragma unroll
    for (int j = 0; j < 16; ++j) {
        a2 += p4[(q * 16 + j) * (NN / 4) + slot];
    }
    __syncthreads();                                  // red[] reuse
    red[t] = a2;
    __syncthreads();
    if (t < 64) {
        const v4f s2 = red[t] + red[t + 64] + red[t + 128] + red[t + 192];
        reinterpret_cast<v4f*>(ws + WS_COL)[slot] = s2;
    }
}

// Fast overflow-safe tanh: copysign(1 - 2/(e^{2|a|}+1), a).
// |a| large -> e = inf -> result ±1 (no NaN). ~1e-6 abs error, threshold 0.28.
__device__ __forceinline__ float fast_tanh(float a) {
    const float e = __expf(2.f * fabsf(a));
    const float t = 1.f - 2.f * __builtin_amdgcn_rcpf(e + 1.f);
    return copysignf(t, a);
}

// Stage 3 (conv): per output row (b,i):
//   s = dot(x[b,i,:], col);  out[b,i] = sum_k tanh(Wt[i][k] * s)
// One 64-lane wave per row — best-measured inner loop (r8): VMEM col reads
// (L1-resident thanks to NT x-loads), 16 NT x-loads fully unrolled for max
// memory-level parallelism, no LDS, no barrier. Runs at ~the m13 per-CU
// stream ceiling (~10 B/cyc/CU).
__global__ void __launch_bounds__(256) conv_kernel(const float* __restrict__ x,
                                                   const float* __restrict__ ws,
                                                   float* __restrict__ out) {
    const int wave = threadIdx.x >> 6;         // 0..3
    const int lane = threadIdx.x & 63;
    const int row  = blockIdx.x * 4 + wave;    // 0 .. 32767  (= b*NN + i)
    const int i    = row & (NN - 1);

    const v4f* __restrict__ xr = reinterpret_cast<const v4f*>(x) + (size_t)row * (NN / 4);
    const v4f* __restrict__ cv = reinterpret_cast<const v4f*>(ws + WS_COL);

    float acc = 0.f;
#pragma unroll
    for (int it = 0; it < NN / 4 / 64; ++it) {      // 16 iterations, fully unrolled
        const v4f a = __builtin_nontemporal_load(&xr[it * 64 + lane]);
        const v4f c = cv[it * 64 + lane];
        const v4f p = a * c;
        acc += p.x + p.y + p.z + p.w;
    }

    // Butterfly reduce: every lane ends with the full dot product s.
#pragma unroll
    for (int off = 32; off >= 1; off >>= 1)
        acc += __shfl_xor(acc, off, 64);

    // Lanes 0..15 each evaluate one filter (coalesced 64B Wt line).
    float r = 0.f;
    if (lane < KK) r = fast_tanh((ws + WS_WT)[i * KK + lane] * acc);
#pragma unroll
    for (int off = 8; off >= 1; off >>= 1)
        r += __shfl_down(r, off, 64);

    if (lane == 0) out[row] = r;
}

extern "C" void kernel_launch(void* const* d_in, const int* in_sizes, int n_in,
                              void* d_out, int out_size, void* d_ws, size_t ws_size,
                              hipStream_t stream) {
    const float* x = (const float*)d_in[0];  // [M, N, N]
    const float* L = (const float*)d_in[1];  // [N, N]
    const float* W = (const float*)d_in[2];  // [K, N]
    float* out = (float*)d_out;              // [M, N] fp32
    float* ws  = (float*)d_ws;               // scratch (col | partial | Wt | ctr)

    // Zero the 16 per-stripe counters (64 B) every call.
    (void)hipMemsetAsync(ws + WS_CTR, 0, 16 * sizeof(int), stream);

    colsum_fused<<<dim3(16, 65), 256, 0, stream>>>(L, W, ws);
    conv_kernel<<<(MM * NN) / 4, 256, 0, stream>>>(x, ws, out);
}

// Round 13
// 100.854 us; speedup vs baseline: 2.5454x; 2.5454x over previous
//
#include <hip/hip_runtime.h>

// Problem constants (from reference): M=8 samples, N=4096, K=16 filters.
#define NN 4096
#define MM 8
#define KK 16

// Native clang vector type (HIP float4 struct is rejected by
// __builtin_nontemporal_load; ext vectors get componentwise ops).
typedef float v4f __attribute__((ext_vector_type(4)));

// ws layout (all write-before-read every call; no memset needed):
//   col     @ 0                : 4096 floats (16 KB)
//   partial @ 4096             : 64 x 4096 floats (1 MB), partial[rg][m]
//   Wt      @ 4096 + 64*4096   : 4096 x 16 floats (256 KB), Wt[i][k]
#define WS_COL     0
#define WS_PARTIAL 4096
#define WS_WT      (4096 + 64 * 4096)

// Stage 1: partial[rg][m] = sum of 64 rows of L in row-group rg, column m.
// Grid (16 col-stripes x 64 row-groups) = 1024 blocks (4/CU). Each thread:
// 16 NT float4 loads (L is stream-once); 4 row-subgroups reduced via a
// 4 KB LDS tree; 64 lanes write one contiguous 1 KB line. No atomics.
__global__ void __launch_bounds__(256) colsum_stage1(const float* __restrict__ L,
                                                     float* __restrict__ ws) {
    const int t  = threadIdx.x;
    const int m4 = blockIdx.x * 64 + (t & 63);        // float4 column slot 0..1023
    const int r0 = blockIdx.y * 64 + (t >> 6) * 16;   // this thread's 16 rows
    const v4f* __restrict__ L4 = reinterpret_cast<const v4f*>(L);
    v4f acc = {0.f, 0.f, 0.f, 0.f};
#pragma unroll
    for (int j = 0; j < 16; ++j) {
        acc += __builtin_nontemporal_load(&L4[(size_t)(r0 + j) * (NN / 4) + m4]);
    }
    __shared__ v4f red[256];
    red[t] = acc;
    __syncthreads();
    if (t < 64) {
        const v4f s = red[t] + red[t + 64] + red[t + 128] + red[t + 192];
        reinterpret_cast<v4f*>(ws + WS_PARTIAL)[blockIdx.y * (NN / 4) + blockIdx.x * 64 + t] = s;
    }
}

// Stage 2: 16 blocks.
//   blocks 0..3  : col[m] = sum_rg partial[rg][m]   (1 MB, cache-resident)
//   blocks 4..15 : Wt[i][k] = W[k][i]               (256 KB transpose)
__global__ void __launch_bounds__(256) colsum_stage2(const float* __restrict__ W,
                                                     float* __restrict__ ws) {
    const int b = blockIdx.x;
    const int t = threadIdx.x;
    if (b < 4) {
        const int slot = b * 256 + t;                // float4 column slot 0..1023
        const v4f* __restrict__ p4 = reinterpret_cast<const v4f*>(ws + WS_PARTIAL);
        v4f acc = {0.f, 0.f, 0.f, 0.f};
#pragma unroll 8
        for (int j = 0; j < 64; ++j) {
            acc += p4[j * (NN / 4) + slot];
        }
        reinterpret_cast<v4f*>(ws + WS_COL)[slot] = acc;
    } else {
        // 12 blocks x 256 threads = 3072 threads over 65536 elements.
        float* __restrict__ Wt = ws + WS_WT;
        for (int o = (b - 4) * 256 + t; o < NN * KK; o += 12 * 256) {
            const int i = o >> 4;                    // simplex index
            const int k = o & 15;                    // filter index
            Wt[o] = W[k * NN + i];
        }
    }
}

// Stage 3 (conv): per output row (b,i):
//   s = dot(x[b,i,:], col);  out[b,i] = sum_k tanh(Wt[i][k] * s)
// One 64-lane wave per row. x is stream-once -> NONTEMPORAL (evict-first),
// keeping the 16 KB col L1-resident (proven −10 µs in r7). VMEM col reads
// (r10 proved LDS staging costs ~2 µs). Full unroll = 16 x-loads in flight
// (r9 proved partial unroll costs ~1 µs). Runs at the m13-measured per-CU
// stream ceiling (~23 GB/s/CU).
__global__ void __launch_bounds__(256) conv_kernel(const float* __restrict__ x,
                                                   const float* __restrict__ ws,
                                                   float* __restrict__ out) {
    const int wave = threadIdx.x >> 6;         // 0..3
    const int lane = threadIdx.x & 63;
    const int row  = blockIdx.x * 4 + wave;    // 0 .. 32767  (= b*NN + i)
    const int i    = row & (NN - 1);

    const v4f* __restrict__ xr = reinterpret_cast<const v4f*>(x) + (size_t)row * (NN / 4);
    const v4f* __restrict__ cv = reinterpret_cast<const v4f*>(ws + WS_COL);

    float acc = 0.f;
#pragma unroll
    for (int it = 0; it < NN / 4 / 64; ++it) {      // 16 iterations, fully unrolled
        const v4f a = __builtin_nontemporal_load(&xr[it * 64 + lane]);
        const v4f c = cv[it * 64 + lane];
        const v4f p = a * c;
        acc += p.x + p.y + p.z + p.w;
    }

    // Butterfly reduce: every lane ends with the full dot product s.
#pragma unroll
    for (int off = 32; off >= 1; off >>= 1)
        acc += __shfl_xor(acc, off, 64);

    // Lanes 0..15 each evaluate one filter (coalesced 64B Wt line).
    float r = 0.f;
    if (lane < KK) r = tanhf((ws + WS_WT)[i * KK + lane] * acc);
#pragma unroll
    for (int off = 8; off >= 1; off >>= 1)
        r += __shfl_down(r, off, 64);

    if (lane == 0) out[row] = r;
}

extern "C" void kernel_launch(void* const* d_in, const int* in_sizes, int n_in,
                              void* d_out, int out_size, void* d_ws, size_t ws_size,
                              hipStream_t stream) {
    const float* x = (const float*)d_in[0];  // [M, N, N]
    const float* L = (const float*)d_in[1];  // [N, N]
    const float* W = (const float*)d_in[2];  // [K, N]
    float* out = (float*)d_out;              // [M, N] fp32
    float* ws  = (float*)d_ws;               // scratch (col | partial | Wt)

    colsum_stage1<<<dim3(16, 64), 256, 0, stream>>>(L, ws);
    colsum_stage2<<<16, 256, 0, stream>>>(W, ws);
    conv_kernel<<<(MM * NN) / 4, 256, 0, stream>>>(x, ws, out);
}